// Round 1
// baseline (578.444 us; speedup 1.0000x reference)
//
#include <hip/hip_runtime.h>
#include <hip/hip_bf16.h>

typedef __bf16 bf16;
typedef __attribute__((ext_vector_type(8))) __bf16 bf16x8;
typedef __attribute__((ext_vector_type(4))) float floatx4;

#define MFMA(a, b, c) __builtin_amdgcn_mfma_f32_16x16x32_bf16(a, b, c, 0, 0, 0)

#define BATCH 32
#define LQ 512
#define LK 512
#define DIM 1024

// ---------------------------------------------------------------------------
// K0a: c[d] = sum_e W[e][d] * b[e]           (grid 16 x 256)
// ---------------------------------------------------------------------------
__global__ __launch_bounds__(256) void k_cvec(const float* __restrict__ W,
                                              const float* __restrict__ bias,
                                              float* __restrict__ c) {
    __shared__ float red[256];
    int t = threadIdx.x;
    int dd = t & 63;
    int eg = t >> 6;
    int d = blockIdx.x * 64 + dd;
    float s = 0.f;
    for (int e = eg * 256; e < eg * 256 + 256; ++e)
        s += W[(size_t)e * DIM + d] * bias[e];
    red[t] = s;
    __syncthreads();
    if (eg == 0) c[d] = red[dd] + red[64 + dd] + red[128 + dd] + red[192 + dd];
}

// ---------------------------------------------------------------------------
// K0b: z[b*LK+m] = c . y[b][m][:]            (grid 4096 x 256, one wave/row)
// ---------------------------------------------------------------------------
__global__ __launch_bounds__(256) void k_zvec(const float* __restrict__ Y,
                                              const float* __restrict__ c,
                                              float* __restrict__ z) {
    int wid = threadIdx.x >> 6, lane = threadIdx.x & 63;
    int row = blockIdx.x * 4 + wid;  // b*LK + m
    const float* yr = Y + (size_t)row * DIM;
    float s = 0.f;
#pragma unroll
    for (int k = 0; k < 4; ++k) {
        int d = k * 256 + lane * 4;
        floatx4 v = *(const floatx4*)(yr + d);
        floatx4 cv = *(const floatx4*)(c + d);
        s += v[0] * cv[0] + v[1] * cv[1] + v[2] * cv[2] + v[3] * cv[3];
    }
#pragma unroll
    for (int off = 32; off; off >>= 1) s += __shfl_down(s, off, 64);
    if (lane == 0) z[row] = s;
}

// ---------------------------------------------------------------------------
// K1: G = W^T W, 3-pass hi/lo MFMA, store Gh/Gl bf16.  grid (16,16), 64x64 tile
// A[i][e] = W[e][i], B[e][j] = W[e][j]  (both transpose-staged from fp32 W)
// ---------------------------------------------------------------------------
__global__ __launch_bounds__(256) void k_gram(const float* __restrict__ W,
                                              bf16* __restrict__ Gh,
                                              bf16* __restrict__ Gl) {
    __shared__ __align__(16) bf16 As[64][72];  // [i][e] hi:0..31 lo:32..63
    __shared__ __align__(16) bf16 Bs[64][72];
    int t = threadIdx.x;
    int lane = t & 63, wid = t >> 6;
    int ln15 = lane & 15, q = lane >> 4;
    int wr = (wid >> 1) * 32, wc = (wid & 1) * 32;
    int i0 = blockIdx.x * 64, j0 = blockIdx.y * 64;
    floatx4 acc[2][2] = {};
    for (int e0 = 0; e0 < DIM; e0 += 32) {
        __syncthreads();
        {
            int ee = t >> 3;           // 0..31
            int c8 = (t & 7) * 8;      // 8 cols per thread (2 float4)
            const float* src = W + (size_t)(e0 + ee) * DIM;
#pragma unroll
            for (int h = 0; h < 2; ++h) {
                floatx4 v = *(const floatx4*)(src + i0 + c8 + h * 4);
#pragma unroll
                for (int j = 0; j < 4; ++j) {
                    float x = v[j];
                    bf16 hi = (bf16)x;
                    As[c8 + h * 4 + j][ee] = hi;
                    As[c8 + h * 4 + j][32 + ee] = (bf16)(x - (float)hi);
                }
                floatx4 u = *(const floatx4*)(src + j0 + c8 + h * 4);
#pragma unroll
                for (int j = 0; j < 4; ++j) {
                    float x = u[j];
                    bf16 hi = (bf16)x;
                    Bs[c8 + h * 4 + j][ee] = hi;
                    Bs[c8 + h * 4 + j][32 + ee] = (bf16)(x - (float)hi);
                }
            }
        }
        __syncthreads();
        bf16x8 ah[2], al[2], bh[2], bl[2];
#pragma unroll
        for (int mi = 0; mi < 2; ++mi) {
            ah[mi] = *(const bf16x8*)&As[wr + mi * 16 + ln15][q * 8];
            al[mi] = *(const bf16x8*)&As[wr + mi * 16 + ln15][32 + q * 8];
        }
#pragma unroll
        for (int ni = 0; ni < 2; ++ni) {
            bh[ni] = *(const bf16x8*)&Bs[wc + ni * 16 + ln15][q * 8];
            bl[ni] = *(const bf16x8*)&Bs[wc + ni * 16 + ln15][32 + q * 8];
        }
#pragma unroll
        for (int mi = 0; mi < 2; ++mi)
#pragma unroll
            for (int ni = 0; ni < 2; ++ni) {
                acc[mi][ni] = MFMA(ah[mi], bh[ni], acc[mi][ni]);
                acc[mi][ni] = MFMA(ah[mi], bl[ni], acc[mi][ni]);
                acc[mi][ni] = MFMA(al[mi], bh[ni], acc[mi][ni]);
            }
    }
#pragma unroll
    for (int mi = 0; mi < 2; ++mi)
#pragma unroll
        for (int ni = 0; ni < 2; ++ni)
#pragma unroll
            for (int r = 0; r < 4; ++r) {
                int i = i0 + wr + mi * 16 + q * 4 + r;
                int j = j0 + wc + ni * 16 + ln15;
                float v = acc[mi][ni][r];
                bf16 hi = (bf16)v;
                Gh[(size_t)i * DIM + j] = hi;
                Gl[(size_t)i * DIM + j] = (bf16)(v - (float)hi);
            }
}

// ---------------------------------------------------------------------------
// K_yT: yT[b][d][m] = bf16(y[b][m][d])       grid (32, 8, 16), 64x64 tiles
// ---------------------------------------------------------------------------
__global__ __launch_bounds__(256) void k_ytrans(const float* __restrict__ Y,
                                                bf16* __restrict__ YT) {
    __shared__ __align__(16) bf16 S[64][72];
    const int b = blockIdx.x, m0 = blockIdx.y * 64, d0 = blockIdx.z * 64;
    const int t = threadIdx.x;
    {
        int row = t >> 2, c16 = (t & 3) * 16;
        const float* src = Y + (size_t)(b * LK + m0 + row) * DIM + d0 + c16;
#pragma unroll
        for (int h = 0; h < 4; ++h) {
            floatx4 v = *(const floatx4*)(src + h * 4);
#pragma unroll
            for (int j = 0; j < 4; ++j) S[row][c16 + h * 4 + j] = (bf16)v[j];
        }
    }
    __syncthreads();
    int dd = t >> 2, ms = (t & 3) * 16;
    union { bf16 h[16]; uint4 u[2]; } o;
#pragma unroll
    for (int j = 0; j < 16; ++j) o.h[j] = S[ms + j][dd];
    bf16* dst = YT + (size_t)(b * DIM + d0 + dd) * LK + m0 + ms;
    *(uint4*)dst = o.u[0];
    *(uint4*)(dst + 8) = o.u[1];
}

// ---------------------------------------------------------------------------
// K2: T = X @ G  (M=16384, N=1024, K=1024), 3-pass hi/lo. T fp32 -> d_out.
// grid (128, 8), 128x128 tile, BK=32. G symmetric -> read rows directly.
// ---------------------------------------------------------------------------
__global__ __launch_bounds__(256) void k_tgemm(const float* __restrict__ X,
                                               const bf16* __restrict__ Gh,
                                               const bf16* __restrict__ Gl,
                                               float* __restrict__ T) {
    __shared__ __align__(16) bf16 As[128][72];
    __shared__ __align__(16) bf16 Bs[128][72];
    const int t = threadIdx.x;
    const int lane = t & 63, wid = t >> 6;
    const int ln15 = lane & 15, q = lane >> 4;
    const int wr = (wid >> 1) * 64, wc = (wid & 1) * 64;
    const int m0 = blockIdx.x * 128, n0 = blockIdx.y * 128;
    floatx4 acc[4][4] = {};
    for (int e0 = 0; e0 < DIM; e0 += 32) {
        __syncthreads();
        {   // A: fp32 x tile, split hi/lo
            int row = t >> 1, sc = (t & 1) * 16;
            const float* src = X + (size_t)(m0 + row) * DIM + e0 + sc;
#pragma unroll
            for (int h = 0; h < 4; ++h) {
                floatx4 v = *(const floatx4*)(src + h * 4);
                union { bf16 h4[4]; uint2 u; } hh, ll;
#pragma unroll
                for (int j = 0; j < 4; ++j) {
                    bf16 hi = (bf16)v[j];
                    hh.h4[j] = hi;
                    ll.h4[j] = (bf16)(v[j] - (float)hi);
                }
                *(uint2*)&As[row][sc + h * 4] = hh.u;
                *(uint2*)&As[row][32 + sc + h * 4] = ll.u;
            }
        }
        {   // B: bf16 G rows (symmetric): Bs[n][k] = G[n0+n][e0+k]
            int row = t >> 1, sk = (t & 1) * 16;
            size_t base = (size_t)(n0 + row) * DIM + e0 + sk;
            *(uint4*)&Bs[row][sk] = *(const uint4*)(Gh + base);
            *(uint4*)&Bs[row][sk + 8] = *(const uint4*)(Gh + base + 8);
            *(uint4*)&Bs[row][32 + sk] = *(const uint4*)(Gl + base);
            *(uint4*)&Bs[row][32 + sk + 8] = *(const uint4*)(Gl + base + 8);
        }
        __syncthreads();
        bf16x8 ah[4], al[4];
#pragma unroll
        for (int mi = 0; mi < 4; ++mi) {
            ah[mi] = *(const bf16x8*)&As[wr + mi * 16 + ln15][q * 8];
            al[mi] = *(const bf16x8*)&As[wr + mi * 16 + ln15][32 + q * 8];
        }
#pragma unroll
        for (int ni = 0; ni < 4; ++ni) {
            bf16x8 bh = *(const bf16x8*)&Bs[wc + ni * 16 + ln15][q * 8];
            bf16x8 bl = *(const bf16x8*)&Bs[wc + ni * 16 + ln15][32 + q * 8];
#pragma unroll
            for (int mi = 0; mi < 4; ++mi) {
                acc[mi][ni] = MFMA(ah[mi], bh, acc[mi][ni]);
                acc[mi][ni] = MFMA(ah[mi], bl, acc[mi][ni]);
                acc[mi][ni] = MFMA(al[mi], bh, acc[mi][ni]);
            }
        }
    }
#pragma unroll
    for (int mi = 0; mi < 4; ++mi)
#pragma unroll
        for (int ni = 0; ni < 4; ++ni)
#pragma unroll
            for (int r = 0; r < 4; ++r)
                T[(size_t)(m0 + wr + mi * 16 + q * 4 + r) * DIM + n0 + wc + ni * 16 + ln15] =
                    acc[mi][ni][r];
}

// ---------------------------------------------------------------------------
// K3: per (b, 64 q-rows): s = T.yT' (3-pass) + z, softmax over m (512),
// write unnormalized P bf16 + row sums.  grid (32, 8), 512 thr (8 waves).
// N split into two 256 halves to fit LDS.
// ---------------------------------------------------------------------------
__global__ __launch_bounds__(512) void k_attn(const float* __restrict__ T,
                                              const float* __restrict__ Y,
                                              const float* __restrict__ Z,
                                              bf16* __restrict__ P,
                                              float* __restrict__ Lsum) {
    __shared__ __align__(16) bf16 As[64][72];
    __shared__ __align__(16) bf16 Bs[256][72];
    __shared__ float redmax[64][4];
    __shared__ float redsum[64][4];
    const int b = blockIdx.x;
    const int l0 = blockIdx.y * 64;
    const int t = threadIdx.x;
    const int lane = t & 63, wid = t >> 6;
    const int ln15 = lane & 15, q = lane >> 4;
    const int wr = (wid >> 2) * 32;   // 0 / 32 : q-row group
    const int wg = wid & 3;           // n-group (64 cols) within half
    floatx4 acc[2][8] = {};

    for (int half = 0; half < 2; ++half) {
        for (int e0 = 0; e0 < DIM; e0 += 32) {
            __syncthreads();
            {   // A: T rows 64 x 32 fp32, split
                int row = t >> 3, c4 = (t & 7) * 4;
                floatx4 v = *(const floatx4*)(T + (size_t)(b * LQ + l0 + row) * DIM + e0 + c4);
                union { bf16 h[4]; uint2 u; } hh, ll;
#pragma unroll
                for (int j = 0; j < 4; ++j) {
                    bf16 hi = (bf16)v[j];
                    hh.h[j] = hi;
                    ll.h[j] = (bf16)(v[j] - (float)hi);
                }
                *(uint2*)&As[row][c4] = hh.u;
                *(uint2*)&As[row][32 + c4] = ll.u;
            }
            {   // B: Y rows [half*256 .. +256) x 32 fp32, split
                int r0 = t >> 3, c4 = (t & 7) * 4;
#pragma unroll
                for (int k = 0; k < 4; ++k) {
                    int row = r0 + k * 64;
                    floatx4 v = *(const floatx4*)(Y + (size_t)(b * LK + half * 256 + row) * DIM + e0 + c4);
                    union { bf16 h[4]; uint2 u; } hh, ll;
#pragma unroll
                    for (int j = 0; j < 4; ++j) {
                        bf16 hi = (bf16)v[j];
                        hh.h[j] = hi;
                        ll.h[j] = (bf16)(v[j] - (float)hi);
                    }
                    *(uint2*)&Bs[row][c4] = hh.u;
                    *(uint2*)&Bs[row][32 + c4] = ll.u;
                }
            }
            __syncthreads();
            bf16x8 ah[2], al[2];
#pragma unroll
            for (int mi = 0; mi < 2; ++mi) {
                ah[mi] = *(const bf16x8*)&As[wr + mi * 16 + ln15][q * 8];
                al[mi] = *(const bf16x8*)&As[wr + mi * 16 + ln15][32 + q * 8];
            }
#pragma unroll
            for (int ni = 0; ni < 4; ++ni) {
                bf16x8 bh = *(const bf16x8*)&Bs[wg * 64 + ni * 16 + ln15][q * 8];
                bf16x8 bl = *(const bf16x8*)&Bs[wg * 64 + ni * 16 + ln15][32 + q * 8];
                const int nn = half * 4 + ni;
#pragma unroll
                for (int mi = 0; mi < 2; ++mi) {
                    acc[mi][nn] = MFMA(ah[mi], bh, acc[mi][nn]);
                    acc[mi][nn] = MFMA(ah[mi], bl, acc[mi][nn]);
                    acc[mi][nn] = MFMA(al[mi], bh, acc[mi][nn]);
                }
            }
        }
    }

    // ---- softmax over 512 cols ----
    float zv[8];
#pragma unroll
    for (int nn = 0; nn < 8; ++nn) {
        int col = (nn >> 2) * 256 + wg * 64 + (nn & 3) * 16 + ln15;
        zv[nn] = Z[b * LK + col];
    }
    float rmax[2][4], rsum[2][4];
#pragma unroll
    for (int mi = 0; mi < 2; ++mi)
#pragma unroll
        for (int r = 0; r < 4; ++r) {
            float m = -3.0e38f;
#pragma unroll
            for (int nn = 0; nn < 8; ++nn) m = fmaxf(m, acc[mi][nn][r] + zv[nn]);
#pragma unroll
            for (int off = 1; off < 16; off <<= 1) m = fmaxf(m, __shfl_xor(m, off, 64));
            rmax[mi][r] = m;
        }
    if (ln15 == 0) {
#pragma unroll
        for (int mi = 0; mi < 2; ++mi)
#pragma unroll
            for (int r = 0; r < 4; ++r) redmax[wr + mi * 16 + q * 4 + r][wg] = rmax[mi][r];
    }
    __syncthreads();
#pragma unroll
    for (int mi = 0; mi < 2; ++mi)
#pragma unroll
        for (int r = 0; r < 4; ++r) {
            int row = wr + mi * 16 + q * 4 + r;
            rmax[mi][r] = fmaxf(fmaxf(redmax[row][0], redmax[row][1]),
                                fmaxf(redmax[row][2], redmax[row][3]));
            rsum[mi][r] = 0.f;
        }
#pragma unroll
    for (int mi = 0; mi < 2; ++mi)
#pragma unroll
        for (int nn = 0; nn < 8; ++nn)
#pragma unroll
            for (int r = 0; r < 4; ++r) {
                float e = __expf(acc[mi][nn][r] + zv[nn] - rmax[mi][r]);
                acc[mi][nn][r] = e;
                rsum[mi][r] += e;
            }
#pragma unroll
    for (int mi = 0; mi < 2; ++mi)
#pragma unroll
        for (int r = 0; r < 4; ++r) {
            float s = rsum[mi][r];
#pragma unroll
            for (int off = 1; off < 16; off <<= 1) s += __shfl_xor(s, off, 64);
            rsum[mi][r] = s;
        }
    if (ln15 == 0) {
#pragma unroll
        for (int mi = 0; mi < 2; ++mi)
#pragma unroll
            for (int r = 0; r < 4; ++r) redsum[wr + mi * 16 + q * 4 + r][wg] = rsum[mi][r];
    }
    __syncthreads();
    if (wg == 0 && ln15 == 0) {
#pragma unroll
        for (int mi = 0; mi < 2; ++mi)
#pragma unroll
            for (int r = 0; r < 4; ++r) {
                int row = wr + mi * 16 + q * 4 + r;
                Lsum[b * LQ + l0 + row] = redsum[row][0] + redsum[row][1] +
                                          redsum[row][2] + redsum[row][3];
            }
    }
    // write unnormalized P (bf16)
#pragma unroll
    for (int mi = 0; mi < 2; ++mi)
#pragma unroll
        for (int nn = 0; nn < 8; ++nn)
#pragma unroll
            for (int r = 0; r < 4; ++r) {
                int row = l0 + wr + mi * 16 + q * 4 + r;
                int col = (nn >> 2) * 256 + wg * 64 + (nn & 3) * 16 + ln15;
                P[(size_t)(b * LQ + row) * LK + col] = (bf16)acc[mi][nn][r];
            }
}

// ---------------------------------------------------------------------------
// K4: O = (P @ y) / Lsum.  Per batch: [512,512]@[512,1024]. grid (32,4,8),
// 128x128 tile, BK=32, plain bf16.  B operand = pre-transposed YT[b][d][m].
// ---------------------------------------------------------------------------
__global__ __launch_bounds__(256) void k_pv(const bf16* __restrict__ P,
                                            const bf16* __restrict__ YT,
                                            const float* __restrict__ Lsum,
                                            float* __restrict__ O) {
    __shared__ __align__(16) bf16 As[128][40];
    __shared__ __align__(16) bf16 Bs[128][40];
    const int t = threadIdx.x;
    const int lane = t & 63, wid = t >> 6;
    const int ln15 = lane & 15, q = lane >> 4;
    const int wr = (wid >> 1) * 64, wc = (wid & 1) * 64;
    const int b = blockIdx.x, m0 = blockIdx.y * 128, n0 = blockIdx.z * 128;
    floatx4 acc[4][4] = {};
    for (int k0 = 0; k0 < LK; k0 += 32) {
        __syncthreads();
        {
            int row = t >> 1, sk = (t & 1) * 16;
            size_t pa = (size_t)(b * LQ + m0 + row) * LK + k0 + sk;
            *(uint4*)&As[row][sk] = *(const uint4*)(P + pa);
            *(uint4*)&As[row][sk + 8] = *(const uint4*)(P + pa + 8);
            size_t ba = (size_t)(b * DIM + n0 + row) * LK + k0 + sk;
            *(uint4*)&Bs[row][sk] = *(const uint4*)(YT + ba);
            *(uint4*)&Bs[row][sk + 8] = *(const uint4*)(YT + ba + 8);
        }
        __syncthreads();
        bf16x8 a[4];
#pragma unroll
        for (int mi = 0; mi < 4; ++mi)
            a[mi] = *(const bf16x8*)&As[wr + mi * 16 + ln15][q * 8];
#pragma unroll
        for (int ni = 0; ni < 4; ++ni) {
            bf16x8 bv = *(const bf16x8*)&Bs[wc + ni * 16 + ln15][q * 8];
#pragma unroll
            for (int mi = 0; mi < 4; ++mi) acc[mi][ni] = MFMA(a[mi], bv, acc[mi][ni]);
        }
    }
    float invl[4][4];
#pragma unroll
    for (int mi = 0; mi < 4; ++mi)
#pragma unroll
        for (int r = 0; r < 4; ++r)
            invl[mi][r] = 1.0f / Lsum[b * LQ + m0 + wr + mi * 16 + q * 4 + r];
#pragma unroll
    for (int mi = 0; mi < 4; ++mi)
#pragma unroll
        for (int ni = 0; ni < 4; ++ni)
#pragma unroll
            for (int r = 0; r < 4; ++r)
                O[(size_t)(b * LQ + m0 + wr + mi * 16 + q * 4 + r) * DIM +
                  n0 + wc + ni * 16 + ln15] = acc[mi][ni][r] * invl[mi][r];
}

// ---------------------------------------------------------------------------
// Workspace layout (bytes):
//   P    : 0          .. 16,777,216   (bf16 [32][512][512])
//   YT   : 16,777,216 .. 50,331,648   (bf16 [32][1024][512])
//   Gh   : 50,331,648 .. 52,428,800
//   Gl   : 52,428,800 .. 54,525,952
//   c    : 54,525,952 .. +4 KB
//   z    : 54,530,048 .. +64 KB
//   Lsum : 54,595,584 .. +64 KB        total ~54.7 MB
// d_out doubles as fp32 scratch for T (= x @ G) between k_tgemm and k_attn;
// k_pv overwrites it with the final result.
// ---------------------------------------------------------------------------
extern "C" void kernel_launch(void* const* d_in, const int* in_sizes, int n_in,
                              void* d_out, int out_size, void* d_ws, size_t ws_size,
                              hipStream_t stream) {
    const float* ix = (const float*)d_in[0];
    const float* io = (const float*)d_in[1];
    const float* W = (const float*)d_in[2];
    const float* bb = (const float*)d_in[3];
    float* out = (float*)d_out;
    char* ws = (char*)d_ws;

    bf16* P = (bf16*)(ws);
    bf16* YT = (bf16*)(ws + 16777216);
    bf16* Gh = (bf16*)(ws + 50331648);
    bf16* Gl = (bf16*)(ws + 52428800);
    float* c = (float*)(ws + 54525952);
    float* z = (float*)(ws + 54530048);
    float* L = (float*)(ws + 54595584);

    k_cvec<<<dim3(16), dim3(256), 0, stream>>>(W, bb, c);
    k_gram<<<dim3(16, 16), dim3(256), 0, stream>>>(W, Gh, Gl);
    k_zvec<<<dim3(4096), dim3(256), 0, stream>>>(io, c, z);
    k_ytrans<<<dim3(32, 8, 16), dim3(256), 0, stream>>>(io, YT);
    k_tgemm<<<dim3(128, 8), dim3(256), 0, stream>>>(ix, Gh, Gl, out);
    k_attn<<<dim3(32, 8), dim3(512), 0, stream>>>(out, io, z, P, L);
    k_pv<<<dim3(32, 4, 8), dim3(256), 0, stream>>>(P, YT, L, out);
}

// Round 2
// 511.388 us; speedup vs baseline: 1.1311x; 1.1311x over previous
//
#include <hip/hip_runtime.h>

typedef _Float16 f16;
typedef __attribute__((ext_vector_type(8))) _Float16 f16x8;
typedef __attribute__((ext_vector_type(4))) _Float16 f16x4;
typedef __attribute__((ext_vector_type(4))) float floatx4;

#define MFMA16(a, b, c) __builtin_amdgcn_mfma_f32_16x16x32_f16(a, b, c, 0, 0, 0)

#define BATCH 32
#define LQ 512
#define LK 512
#define DIM 1024

// async global->LDS, 16B per lane. LDS dest must be base + lane*16 within wave.
__device__ __forceinline__ void glds16(const void* g, void* l) {
    __builtin_amdgcn_global_load_lds(
        (const __attribute__((address_space(1))) unsigned int*)g,
        (__attribute__((address_space(3))) unsigned int*)l, 16, 0, 0);
}

// ---------------------------------------------------------------------------
// K0a: c[d] = sum_e W[e][d] * bias[e]
// ---------------------------------------------------------------------------
__global__ __launch_bounds__(256) void k_cvec(const float* __restrict__ W,
                                              const float* __restrict__ bias,
                                              float* __restrict__ c) {
    __shared__ float red[256];
    int t = threadIdx.x;
    int dd = t & 63, eg = t >> 6;
    int d = blockIdx.x * 64 + dd;
    float s = 0.f;
    for (int e = eg * 256; e < eg * 256 + 256; ++e)
        s += W[(size_t)e * DIM + d] * bias[e];
    red[t] = s;
    __syncthreads();
    if (eg == 0) c[d] = red[dd] + red[64 + dd] + red[128 + dd] + red[192 + dd];
}

// ---------------------------------------------------------------------------
// K0b: Y16 = fp16(Y) (row-major) and z[row] = c . Y[row]   (grid 4096 x 256)
// ---------------------------------------------------------------------------
__global__ __launch_bounds__(256) void k_prep_y(const float* __restrict__ Y,
                                                const float* __restrict__ c,
                                                f16* __restrict__ Y16,
                                                float* __restrict__ z) {
    int wid = threadIdx.x >> 6, lane = threadIdx.x & 63;
    int row = blockIdx.x * 4 + wid;  // b*LK + m
    const float* yr = Y + (size_t)row * DIM;
    f16* orow = Y16 + (size_t)row * DIM;
    float s = 0.f;
#pragma unroll
    for (int k = 0; k < 4; ++k) {
        int d = k * 256 + lane * 4;
        floatx4 v = *(const floatx4*)(yr + d);
        floatx4 cv = *(const floatx4*)(c + d);
        s += v[0] * cv[0] + v[1] * cv[1] + v[2] * cv[2] + v[3] * cv[3];
        f16x4 o;
        o[0] = (f16)v[0]; o[1] = (f16)v[1]; o[2] = (f16)v[2]; o[3] = (f16)v[3];
        *(f16x4*)(orow + d) = o;
    }
#pragma unroll
    for (int off = 32; off; off >>= 1) s += __shfl_down(s, off, 64);
    if (lane == 0) z[row] = s;
}

// ---------------------------------------------------------------------------
// K0c: X16 = fp16(X)    (grid 8192 x 256, 8 elems/thread)
// ---------------------------------------------------------------------------
__global__ __launch_bounds__(256) void k_xsplit(const float* __restrict__ X,
                                                f16* __restrict__ X16) {
    size_t i = ((size_t)blockIdx.x * 256 + threadIdx.x) * 8;
    floatx4 a = *(const floatx4*)(X + i);
    floatx4 b = *(const floatx4*)(X + i + 4);
    f16x8 o;
    o[0] = (f16)a[0]; o[1] = (f16)a[1]; o[2] = (f16)a[2]; o[3] = (f16)a[3];
    o[4] = (f16)b[0]; o[5] = (f16)b[1]; o[6] = (f16)b[2]; o[7] = (f16)b[3];
    *(f16x8*)(X16 + i) = o;
}

// ---------------------------------------------------------------------------
// K1: G = W^T W  (3-pass fp16 hi/lo -> near-exact), store Gh/Gl fp16.
// grid (16,16), 64x64 tile.
// ---------------------------------------------------------------------------
__global__ __launch_bounds__(256) void k_gram(const float* __restrict__ W,
                                              f16* __restrict__ Gh,
                                              f16* __restrict__ Gl) {
    __shared__ __align__(16) f16 As[64][72];  // [i][e] hi:0..31 lo:32..63
    __shared__ __align__(16) f16 Bs[64][72];
    int t = threadIdx.x;
    int lane = t & 63, wid = t >> 6;
    int ln15 = lane & 15, q = lane >> 4;
    int wr = (wid >> 1) * 32, wc = (wid & 1) * 32;
    int i0 = blockIdx.x * 64, j0 = blockIdx.y * 64;
    floatx4 acc[2][2] = {};
    for (int e0 = 0; e0 < DIM; e0 += 32) {
        __syncthreads();
        {
            int ee = t >> 3;
            int c8 = (t & 7) * 8;
            const float* src = W + (size_t)(e0 + ee) * DIM;
#pragma unroll
            for (int h = 0; h < 2; ++h) {
                floatx4 v = *(const floatx4*)(src + i0 + c8 + h * 4);
#pragma unroll
                for (int j = 0; j < 4; ++j) {
                    f16 hi = (f16)v[j];
                    As[c8 + h * 4 + j][ee] = hi;
                    As[c8 + h * 4 + j][32 + ee] = (f16)(v[j] - (float)hi);
                }
                floatx4 u = *(const floatx4*)(src + j0 + c8 + h * 4);
#pragma unroll
                for (int j = 0; j < 4; ++j) {
                    f16 hi = (f16)u[j];
                    Bs[c8 + h * 4 + j][ee] = hi;
                    Bs[c8 + h * 4 + j][32 + ee] = (f16)(u[j] - (float)hi);
                }
            }
        }
        __syncthreads();
        f16x8 ah[2], al[2], bh[2], bl[2];
#pragma unroll
        for (int mi = 0; mi < 2; ++mi) {
            ah[mi] = *(const f16x8*)&As[wr + mi * 16 + ln15][q * 8];
            al[mi] = *(const f16x8*)&As[wr + mi * 16 + ln15][32 + q * 8];
        }
#pragma unroll
        for (int ni = 0; ni < 2; ++ni) {
            bh[ni] = *(const f16x8*)&Bs[wc + ni * 16 + ln15][q * 8];
            bl[ni] = *(const f16x8*)&Bs[wc + ni * 16 + ln15][32 + q * 8];
        }
#pragma unroll
        for (int mi = 0; mi < 2; ++mi)
#pragma unroll
            for (int ni = 0; ni < 2; ++ni) {
                acc[mi][ni] = MFMA16(ah[mi], bh[ni], acc[mi][ni]);
                acc[mi][ni] = MFMA16(ah[mi], bl[ni], acc[mi][ni]);
                acc[mi][ni] = MFMA16(al[mi], bh[ni], acc[mi][ni]);
            }
    }
#pragma unroll
    for (int mi = 0; mi < 2; ++mi)
#pragma unroll
        for (int ni = 0; ni < 2; ++ni)
#pragma unroll
            for (int r = 0; r < 4; ++r) {
                int i = i0 + wr + mi * 16 + q * 4 + r;
                int j = j0 + wc + ni * 16 + ln15;
                float v = acc[mi][ni][r];
                f16 hi = (f16)v;
                Gh[(size_t)i * DIM + j] = hi;
                Gl[(size_t)i * DIM + j] = (f16)(v - (float)hi);
            }
}

// ---------------------------------------------------------------------------
// K2: T = X16 @ (Gh + Gl), 2-pass fp16. M=16384, N=K=1024.
// 128x128 tile, BK=32, global_load_lds staging. Th/Tl fp16 -> d_out scratch.
// ---------------------------------------------------------------------------
__global__ __launch_bounds__(256) void k_tgemm(const f16* __restrict__ X16,
                                               const f16* __restrict__ Gh,
                                               const f16* __restrict__ Gl,
                                               f16* __restrict__ Th,
                                               f16* __restrict__ Tl) {
    __shared__ __align__(16) f16 sA[128 * 32];
    __shared__ __align__(16) f16 sBh[128 * 32];
    __shared__ __align__(16) f16 sBl[128 * 32];
    const int t = threadIdx.x;
    const int lane = t & 63, wid = t >> 6;
    const int ln15 = lane & 15, q = lane >> 4;
    const int wr = (wid >> 1) * 64, wc = (wid & 1) * 64;
    const int m0 = blockIdx.x * 128, n0 = blockIdx.y * 128;
    floatx4 acc[4][4] = {};
    for (int e0 = 0; e0 < DIM; e0 += 32) {
        __syncthreads();
#pragma unroll
        for (int is = 0; is < 2; ++is) {
            int ff = is * 4096 + t * 16;            // byte offset in 8KB tile
            int row = ff >> 6, col = (ff & 63) >> 1;
            glds16(X16 + (size_t)(m0 + row) * DIM + e0 + col, (char*)sA + ff);
            glds16(Gh + (size_t)(n0 + row) * DIM + e0 + col, (char*)sBh + ff);
            glds16(Gl + (size_t)(n0 + row) * DIM + e0 + col, (char*)sBl + ff);
        }
        __syncthreads();
        f16x8 a[4];
#pragma unroll
        for (int mi = 0; mi < 4; ++mi)
            a[mi] = *(const f16x8*)&sA[(wr + mi * 16 + ln15) * 32 + q * 8];
#pragma unroll
        for (int ni = 0; ni < 4; ++ni) {
            f16x8 bh = *(const f16x8*)&sBh[(wc + ni * 16 + ln15) * 32 + q * 8];
            f16x8 bl = *(const f16x8*)&sBl[(wc + ni * 16 + ln15) * 32 + q * 8];
#pragma unroll
            for (int mi = 0; mi < 4; ++mi) {
                acc[mi][ni] = MFMA16(a[mi], bh, acc[mi][ni]);
                acc[mi][ni] = MFMA16(a[mi], bl, acc[mi][ni]);
            }
        }
    }
#pragma unroll
    for (int mi = 0; mi < 4; ++mi)
#pragma unroll
        for (int ni = 0; ni < 4; ++ni)
#pragma unroll
            for (int r = 0; r < 4; ++r) {
                size_t idx = (size_t)(m0 + wr + mi * 16 + q * 4 + r) * DIM +
                             n0 + wc + ni * 16 + ln15;
                float v = acc[mi][ni][r];
                f16 hi = (f16)v;
                Th[idx] = hi;
                Tl[idx] = (f16)(v - (float)hi);
            }
}

// ---------------------------------------------------------------------------
// K_yT: YT16[b][d][m] = Y16[b][m][d]   (grid (32,8,16), 64x64 tiles)
// ---------------------------------------------------------------------------
__global__ __launch_bounds__(256) void k_ytrans(const f16* __restrict__ Y16,
                                                f16* __restrict__ YT) {
    __shared__ __align__(16) f16 S[64][72];
    const int b = blockIdx.x, m0 = blockIdx.y * 64, d0 = blockIdx.z * 64;
    const int t = threadIdx.x;
    {
        int row = t >> 2, cg = (t & 3) * 16;
        const f16* src = Y16 + (size_t)(b * LK + m0 + row) * DIM + d0 + cg;
        *(uint4*)&S[row][cg] = *(const uint4*)src;
        *(uint4*)&S[row][cg + 8] = *(const uint4*)(src + 8);
    }
    __syncthreads();
    int dd = t >> 2, ms = (t & 3) * 16;
    union { f16 h[16]; uint4 u[2]; } o;
#pragma unroll
    for (int j = 0; j < 16; ++j) o.h[j] = S[ms + j][dd];
    f16* dst = YT + (size_t)(b * DIM + d0 + dd) * LK + m0 + ms;
    *(uint4*)dst = o.u[0];
    *(uint4*)(dst + 8) = o.u[1];
}

// ---------------------------------------------------------------------------
// K3: per (b, 64 q-rows): s = (Th+Tl) . Y16^T + z, softmax over 512 keys,
// write unnormalized P fp16 + row sums. grid (32,8), 512 thr (8 waves).
// Each wave owns 64 key-columns. glds staging, BK=32.
// LDS: Th 4KB | Tl 4KB | Y 32KB (contiguous for glds flat mapping).
// ---------------------------------------------------------------------------
__global__ __launch_bounds__(512) void k_attn(const f16* __restrict__ Th,
                                              const f16* __restrict__ Tl,
                                              const f16* __restrict__ Y16,
                                              const float* __restrict__ Z,
                                              f16* __restrict__ P,
                                              float* __restrict__ Lsum) {
    __shared__ __align__(16) f16 sS[20480];  // 40960 B
    __shared__ float redmax[64][8];
    __shared__ float redsum[64][8];
    const int b = blockIdx.x;
    const int l0 = blockIdx.y * 64;
    const int t = threadIdx.x;
    const int lane = t & 63, w = t >> 6;
    const int ln15 = lane & 15, q = lane >> 4;
    floatx4 acc[4][4] = {};  // [row-frag][col-frag within wave's 64 cols]

    for (int e0 = 0; e0 < DIM; e0 += 32) {
        __syncthreads();
#pragma unroll
        for (int is = 0; is < 5; ++is) {
            int ff = is * 8192 + t * 16;
            const f16* g;
            if (ff < 4096) {
                g = Th + (size_t)(b * LQ + l0 + (ff >> 6)) * DIM + e0 + ((ff & 63) >> 1);
            } else if (ff < 8192) {
                int f2 = ff - 4096;
                g = Tl + (size_t)(b * LQ + l0 + (f2 >> 6)) * DIM + e0 + ((f2 & 63) >> 1);
            } else {
                int f2 = ff - 8192;
                g = Y16 + (size_t)(b * LK + (f2 >> 6)) * DIM + e0 + ((f2 & 63) >> 1);
            }
            glds16(g, (char*)sS + ff);
        }
        __syncthreads();
        f16x8 th[4], tl[4];
#pragma unroll
        for (int mi = 0; mi < 4; ++mi) {
            th[mi] = *(const f16x8*)&sS[(mi * 16 + ln15) * 32 + q * 8];
            tl[mi] = *(const f16x8*)&sS[2048 + (mi * 16 + ln15) * 32 + q * 8];
        }
#pragma unroll
        for (int ni = 0; ni < 4; ++ni) {
            f16x8 y = *(const f16x8*)&sS[4096 + (w * 64 + ni * 16 + ln15) * 32 + q * 8];
#pragma unroll
            for (int mi = 0; mi < 4; ++mi) {
                acc[mi][ni] = MFMA16(th[mi], y, acc[mi][ni]);
                acc[mi][ni] = MFMA16(tl[mi], y, acc[mi][ni]);
            }
        }
    }

    // ---- softmax over 512 cols (8 waves x 64 cols) ----
    float zv[4];
#pragma unroll
    for (int ni = 0; ni < 4; ++ni) zv[ni] = Z[b * LK + w * 64 + ni * 16 + ln15];

    float rmx[4][4];
#pragma unroll
    for (int mi = 0; mi < 4; ++mi)
#pragma unroll
        for (int r = 0; r < 4; ++r) {
            float m = -3.0e38f;
#pragma unroll
            for (int ni = 0; ni < 4; ++ni) m = fmaxf(m, acc[mi][ni][r] + zv[ni]);
#pragma unroll
            for (int off = 1; off < 16; off <<= 1) m = fmaxf(m, __shfl_xor(m, off, 64));
            rmx[mi][r] = m;
        }
    if (ln15 == 0) {
#pragma unroll
        for (int mi = 0; mi < 4; ++mi)
#pragma unroll
            for (int r = 0; r < 4; ++r) redmax[mi * 16 + q * 4 + r][w] = rmx[mi][r];
    }
    __syncthreads();
#pragma unroll
    for (int mi = 0; mi < 4; ++mi)
#pragma unroll
        for (int r = 0; r < 4; ++r) {
            int row = mi * 16 + q * 4 + r;
            float m = redmax[row][0];
#pragma unroll
            for (int j = 1; j < 8; ++j) m = fmaxf(m, redmax[row][j]);
            rmx[mi][r] = m;
        }
    float rsm[4][4] = {};
#pragma unroll
    for (int mi = 0; mi < 4; ++mi)
#pragma unroll
        for (int ni = 0; ni < 4; ++ni)
#pragma unroll
            for (int r = 0; r < 4; ++r) {
                float e = __expf(acc[mi][ni][r] + zv[ni] - rmx[mi][r]);
                acc[mi][ni][r] = e;
                rsm[mi][r] += e;
            }
#pragma unroll
    for (int mi = 0; mi < 4; ++mi)
#pragma unroll
        for (int r = 0; r < 4; ++r) {
            float s = rsm[mi][r];
#pragma unroll
            for (int off = 1; off < 16; off <<= 1) s += __shfl_xor(s, off, 64);
            rsm[mi][r] = s;
        }
    if (ln15 == 0) {
#pragma unroll
        for (int mi = 0; mi < 4; ++mi)
#pragma unroll
            for (int r = 0; r < 4; ++r) redsum[mi * 16 + q * 4 + r][w] = rsm[mi][r];
    }
    __syncthreads();
    if (w == 0 && ln15 == 0) {
#pragma unroll
        for (int mi = 0; mi < 4; ++mi)
#pragma unroll
            for (int r = 0; r < 4; ++r) {
                int row = mi * 16 + q * 4 + r;
                float s = 0.f;
#pragma unroll
                for (int j = 0; j < 8; ++j) s += redsum[row][j];
                Lsum[b * LQ + l0 + row] = s;
            }
    }
#pragma unroll
    for (int mi = 0; mi < 4; ++mi)
#pragma unroll
        for (int ni = 0; ni < 4; ++ni)
#pragma unroll
            for (int r = 0; r < 4; ++r) {
                int row = l0 + mi * 16 + q * 4 + r;
                int col = w * 64 + ni * 16 + ln15;
                P[(size_t)(b * LQ + row) * LK + col] = (f16)acc[mi][ni][r];
            }
}

// ---------------------------------------------------------------------------
// K4: O = (P @ y) / Lsum  via YT16. grid (32,4,8), 128x128 tile, BK=32, glds.
// ---------------------------------------------------------------------------
__global__ __launch_bounds__(256) void k_pv(const f16* __restrict__ P,
                                            const f16* __restrict__ YT,
                                            const float* __restrict__ Lsum,
                                            float* __restrict__ O) {
    __shared__ __align__(16) f16 sA[128 * 32];
    __shared__ __align__(16) f16 sB[128 * 32];
    const int t = threadIdx.x;
    const int lane = t & 63, wid = t >> 6;
    const int ln15 = lane & 15, q = lane >> 4;
    const int wr = (wid >> 1) * 64, wc = (wid & 1) * 64;
    const int b = blockIdx.x, m0 = blockIdx.y * 128, n0 = blockIdx.z * 128;
    floatx4 acc[4][4] = {};
    for (int k0 = 0; k0 < LK; k0 += 32) {
        __syncthreads();
#pragma unroll
        for (int is = 0; is < 2; ++is) {
            int ff = is * 4096 + t * 16;
            int row = ff >> 6, col = (ff & 63) >> 1;
            glds16(P + (size_t)(b * LQ + m0 + row) * LK + k0 + col, (char*)sA + ff);
            glds16(YT + (size_t)(b * DIM + n0 + row) * LK + k0 + col, (char*)sB + ff);
        }
        __syncthreads();
        f16x8 a[4];
#pragma unroll
        for (int mi = 0; mi < 4; ++mi)
            a[mi] = *(const f16x8*)&sA[(wr + mi * 16 + ln15) * 32 + q * 8];
#pragma unroll
        for (int ni = 0; ni < 4; ++ni) {
            f16x8 bv = *(const f16x8*)&sB[(wc + ni * 16 + ln15) * 32 + q * 8];
#pragma unroll
            for (int mi = 0; mi < 4; ++mi) acc[mi][ni] = MFMA16(a[mi], bv, acc[mi][ni]);
        }
    }
    float invl[4][4];
#pragma unroll
    for (int mi = 0; mi < 4; ++mi)
#pragma unroll
        for (int r = 0; r < 4; ++r)
            invl[mi][r] = 1.0f / Lsum[b * LQ + m0 + wr + mi * 16 + q * 4 + r];
#pragma unroll
    for (int mi = 0; mi < 4; ++mi)
#pragma unroll
        for (int ni = 0; ni < 4; ++ni)
#pragma unroll
            for (int r = 0; r < 4; ++r)
                O[(size_t)(b * LQ + m0 + wr + mi * 16 + q * 4 + r) * DIM +
                  n0 + wc + ni * 16 + ln15] = acc[mi][ni][r] * invl[mi][r];
}

// ---------------------------------------------------------------------------
// Workspace layout (bytes), total ~84.1 MiB:
//   A:  0         X16 fp16 [16384][1024] (33,554,432); after k_tgemm reused
//                 for YT16 fp16 [32][1024][512]
//   B:  33554432  Y16 fp16 [32][512][1024] (33,554,432)
//   P:  67108864  P fp16 [32][512][512]    (16,777,216)
//   Gh: 83886080  (2,097,152)   Gl: 85983232 (2,097,152)
//   c:  88080384  (4096)  z: 88084480 (65536)  L: 88150016 (65536)
// d_out doubles as Th|Tl fp16 scratch (33.5MB+33.5MB) between k_tgemm and
// k_attn; k_pv overwrites it with the final fp32 result.
// ---------------------------------------------------------------------------
extern "C" void kernel_launch(void* const* d_in, const int* in_sizes, int n_in,
                              void* d_out, int out_size, void* d_ws, size_t ws_size,
                              hipStream_t stream) {
    const float* ix = (const float*)d_in[0];
    const float* io = (const float*)d_in[1];
    const float* W = (const float*)d_in[2];
    const float* bb = (const float*)d_in[3];
    float* out = (float*)d_out;
    char* ws = (char*)d_ws;

    f16* X16 = (f16*)(ws);
    f16* YT16 = (f16*)(ws);  // same region, used after k_tgemm
    f16* Y16 = (f16*)(ws + 33554432);
    f16* P = (f16*)(ws + 67108864);
    f16* Gh = (f16*)(ws + 83886080);
    f16* Gl = (f16*)(ws + 85983232);
    float* c = (float*)(ws + 88080384);
    float* z = (float*)(ws + 88084480);
    float* L = (float*)(ws + 88150016);

    f16* Th = (f16*)d_out;
    f16* Tl = Th + (size_t)16384 * 1024;

    k_cvec<<<dim3(16), dim3(256), 0, stream>>>(W, bb, c);
    k_gram<<<dim3(16, 16), dim3(256), 0, stream>>>(W, Gh, Gl);
    k_prep_y<<<dim3(4096), dim3(256), 0, stream>>>(io, c, Y16, z);
    k_xsplit<<<dim3(8192), dim3(256), 0, stream>>>(ix, X16);
    k_tgemm<<<dim3(128, 8), dim3(256), 0, stream>>>(X16, Gh, Gl, Th, Tl);
    k_ytrans<<<dim3(32, 8, 16), dim3(256), 0, stream>>>(Y16, YT16);
    k_attn<<<dim3(32, 8), dim3(512), 0, stream>>>(Th, Tl, Y16, z, P, L);
    k_pv<<<dim3(32, 4, 8), dim3(256), 0, stream>>>(P, YT16, L, out);
}

// Round 3
// 402.286 us; speedup vs baseline: 1.4379x; 1.2712x over previous
//
#include <hip/hip_runtime.h>

typedef _Float16 f16;
typedef __attribute__((ext_vector_type(8))) _Float16 f16x8;
typedef __attribute__((ext_vector_type(4))) _Float16 f16x4;
typedef __attribute__((ext_vector_type(4))) float floatx4;

#define MFMA16(a, b, c) __builtin_amdgcn_mfma_f32_16x16x32_f16(a, b, c, 0, 0, 0)

#define BATCH 32
#define LQ 512
#define LK 512
#define DIM 1024

// async global->LDS, 16B per lane. LDS dest must be base + lane*16 within wave.
__device__ __forceinline__ void glds16(const void* g, void* l) {
    __builtin_amdgcn_global_load_lds(
        (const __attribute__((address_space(1))) unsigned int*)g,
        (__attribute__((address_space(3))) unsigned int*)l, 16, 0, 0);
}

// ---------------------------------------------------------------------------
// K0a stage 1: partial[ec][d] = sum_{e in 64-chunk ec} W[e][d]*bias[e]
// grid (16,16) x 256 — 256 blocks, all CUs busy, coalesced rows.
// ---------------------------------------------------------------------------
__global__ __launch_bounds__(256) void k_cvec1(const float* __restrict__ W,
                                               const float* __restrict__ bias,
                                               float* __restrict__ partial) {
    __shared__ float red[256];
    int t = threadIdx.x;
    int dd = t & 63, eg = t >> 6;                 // 4 e-groups of 16
    int d = blockIdx.x * 64 + dd;
    int e0 = blockIdx.y * 64 + eg * 16;
    float s = 0.f;
#pragma unroll
    for (int i = 0; i < 16; ++i)
        s += W[(size_t)(e0 + i) * DIM + d] * bias[e0 + i];
    red[t] = s;
    __syncthreads();
    if (eg == 0)
        partial[blockIdx.y * DIM + d] =
            red[dd] + red[64 + dd] + red[128 + dd] + red[192 + dd];
}

// K0a stage 2: c[d] = sum_ec partial[ec][d]   (grid 4 x 256)
__global__ __launch_bounds__(256) void k_cvec2(const float* __restrict__ partial,
                                               float* __restrict__ c) {
    int d = blockIdx.x * 256 + threadIdx.x;
    float s = 0.f;
#pragma unroll
    for (int j = 0; j < 16; ++j) s += partial[j * DIM + d];
    c[d] = s;
}

// ---------------------------------------------------------------------------
// K0b: Y16 = fp16(Y) (row-major) and z[row] = c . Y[row]   (grid 4096 x 256)
// ---------------------------------------------------------------------------
__global__ __launch_bounds__(256) void k_prep_y(const float* __restrict__ Y,
                                                const float* __restrict__ c,
                                                f16* __restrict__ Y16,
                                                float* __restrict__ z) {
    int wid = threadIdx.x >> 6, lane = threadIdx.x & 63;
    int row = blockIdx.x * 4 + wid;  // b*LK + m
    const float* yr = Y + (size_t)row * DIM;
    f16* orow = Y16 + (size_t)row * DIM;
    float s = 0.f;
#pragma unroll
    for (int k = 0; k < 4; ++k) {
        int d = k * 256 + lane * 4;
        floatx4 v = *(const floatx4*)(yr + d);
        floatx4 cv = *(const floatx4*)(c + d);
        s += v[0] * cv[0] + v[1] * cv[1] + v[2] * cv[2] + v[3] * cv[3];
        f16x4 o;
        o[0] = (f16)v[0]; o[1] = (f16)v[1]; o[2] = (f16)v[2]; o[3] = (f16)v[3];
        *(f16x4*)(orow + d) = o;
    }
#pragma unroll
    for (int off = 32; off; off >>= 1) s += __shfl_down(s, off, 64);
    if (lane == 0) z[row] = s;
}

// ---------------------------------------------------------------------------
// K0c: X16 = fp16(X)    (grid 8192 x 256, 8 elems/thread)
// ---------------------------------------------------------------------------
__global__ __launch_bounds__(256) void k_xsplit(const float* __restrict__ X,
                                                f16* __restrict__ X16) {
    size_t i = ((size_t)blockIdx.x * 256 + threadIdx.x) * 8;
    floatx4 a = *(const floatx4*)(X + i);
    floatx4 b = *(const floatx4*)(X + i + 4);
    f16x8 o;
    o[0] = (f16)a[0]; o[1] = (f16)a[1]; o[2] = (f16)a[2]; o[3] = (f16)a[3];
    o[4] = (f16)b[0]; o[5] = (f16)b[1]; o[6] = (f16)b[2]; o[7] = (f16)b[3];
    *(f16x8*)(X16 + i) = o;
}

// ---------------------------------------------------------------------------
// K1: G = W^T W  (3-pass fp16 hi/lo -> near-exact), store Gh/Gl fp16.
// grid (16,16), 64x64 tile.
// ---------------------------------------------------------------------------
__global__ __launch_bounds__(256) void k_gram(const float* __restrict__ W,
                                              f16* __restrict__ Gh,
                                              f16* __restrict__ Gl) {
    __shared__ __align__(16) f16 As[64][72];  // [i][e] hi:0..31 lo:32..63
    __shared__ __align__(16) f16 Bs[64][72];
    int t = threadIdx.x;
    int lane = t & 63, wid = t >> 6;
    int ln15 = lane & 15, q = lane >> 4;
    int wr = (wid >> 1) * 32, wc = (wid & 1) * 32;
    int i0 = blockIdx.x * 64, j0 = blockIdx.y * 64;
    floatx4 acc[2][2] = {};
    for (int e0 = 0; e0 < DIM; e0 += 32) {
        __syncthreads();
        {
            int ee = t >> 3;
            int c8 = (t & 7) * 8;
            const float* src = W + (size_t)(e0 + ee) * DIM;
#pragma unroll
            for (int h = 0; h < 2; ++h) {
                floatx4 v = *(const floatx4*)(src + i0 + c8 + h * 4);
#pragma unroll
                for (int j = 0; j < 4; ++j) {
                    f16 hi = (f16)v[j];
                    As[c8 + h * 4 + j][ee] = hi;
                    As[c8 + h * 4 + j][32 + ee] = (f16)(v[j] - (float)hi);
                }
                floatx4 u = *(const floatx4*)(src + j0 + c8 + h * 4);
#pragma unroll
                for (int j = 0; j < 4; ++j) {
                    f16 hi = (f16)u[j];
                    Bs[c8 + h * 4 + j][ee] = hi;
                    Bs[c8 + h * 4 + j][32 + ee] = (f16)(u[j] - (float)hi);
                }
            }
        }
        __syncthreads();
        f16x8 ah[2], al[2], bh[2], bl[2];
#pragma unroll
        for (int mi = 0; mi < 2; ++mi) {
            ah[mi] = *(const f16x8*)&As[wr + mi * 16 + ln15][q * 8];
            al[mi] = *(const f16x8*)&As[wr + mi * 16 + ln15][32 + q * 8];
        }
#pragma unroll
        for (int ni = 0; ni < 2; ++ni) {
            bh[ni] = *(const f16x8*)&Bs[wc + ni * 16 + ln15][q * 8];
            bl[ni] = *(const f16x8*)&Bs[wc + ni * 16 + ln15][32 + q * 8];
        }
#pragma unroll
        for (int mi = 0; mi < 2; ++mi)
#pragma unroll
            for (int ni = 0; ni < 2; ++ni) {
                acc[mi][ni] = MFMA16(ah[mi], bh[ni], acc[mi][ni]);
                acc[mi][ni] = MFMA16(ah[mi], bl[ni], acc[mi][ni]);
                acc[mi][ni] = MFMA16(al[mi], bh[ni], acc[mi][ni]);
            }
    }
#pragma unroll
    for (int mi = 0; mi < 2; ++mi)
#pragma unroll
        for (int ni = 0; ni < 2; ++ni)
#pragma unroll
            for (int r = 0; r < 4; ++r) {
                int i = i0 + wr + mi * 16 + q * 4 + r;
                int j = j0 + wc + ni * 16 + ln15;
                float v = acc[mi][ni][r];
                f16 hi = (f16)v;
                Gh[(size_t)i * DIM + j] = hi;
                Gl[(size_t)i * DIM + j] = (f16)(v - (float)hi);
            }
}

// ---------------------------------------------------------------------------
// K2: T = X16 @ (Gh + Gl), 2-pass fp16. M=16384, N=K=1024.
// 128x128 tile, BK=32, global_load_lds staging. Th/Tl fp16 -> d_out scratch.
// ---------------------------------------------------------------------------
__global__ __launch_bounds__(256) void k_tgemm(const f16* __restrict__ X16,
                                               const f16* __restrict__ Gh,
                                               const f16* __restrict__ Gl,
                                               f16* __restrict__ Th,
                                               f16* __restrict__ Tl) {
    __shared__ __align__(16) f16 sA[128 * 32];
    __shared__ __align__(16) f16 sBh[128 * 32];
    __shared__ __align__(16) f16 sBl[128 * 32];
    const int t = threadIdx.x;
    const int lane = t & 63, wid = t >> 6;
    const int ln15 = lane & 15, q = lane >> 4;
    const int wr = (wid >> 1) * 64, wc = (wid & 1) * 64;
    const int m0 = blockIdx.x * 128, n0 = blockIdx.y * 128;
    floatx4 acc[4][4] = {};
    for (int e0 = 0; e0 < DIM; e0 += 32) {
        __syncthreads();
#pragma unroll
        for (int is = 0; is < 2; ++is) {
            int ff = is * 4096 + t * 16;            // byte offset in 8KB tile
            int row = ff >> 6, col = (ff & 63) >> 1;
            glds16(X16 + (size_t)(m0 + row) * DIM + e0 + col, (char*)sA + ff);
            glds16(Gh + (size_t)(n0 + row) * DIM + e0 + col, (char*)sBh + ff);
            glds16(Gl + (size_t)(n0 + row) * DIM + e0 + col, (char*)sBl + ff);
        }
        __syncthreads();
        f16x8 a[4];
#pragma unroll
        for (int mi = 0; mi < 4; ++mi)
            a[mi] = *(const f16x8*)&sA[(wr + mi * 16 + ln15) * 32 + q * 8];
#pragma unroll
        for (int ni = 0; ni < 4; ++ni) {
            f16x8 bh = *(const f16x8*)&sBh[(wc + ni * 16 + ln15) * 32 + q * 8];
            f16x8 bl = *(const f16x8*)&sBl[(wc + ni * 16 + ln15) * 32 + q * 8];
#pragma unroll
            for (int mi = 0; mi < 4; ++mi) {
                acc[mi][ni] = MFMA16(a[mi], bh, acc[mi][ni]);
                acc[mi][ni] = MFMA16(a[mi], bl, acc[mi][ni]);
            }
        }
    }
#pragma unroll
    for (int mi = 0; mi < 4; ++mi)
#pragma unroll
        for (int ni = 0; ni < 4; ++ni)
#pragma unroll
            for (int r = 0; r < 4; ++r) {
                size_t idx = (size_t)(m0 + wr + mi * 16 + q * 4 + r) * DIM +
                             n0 + wc + ni * 16 + ln15;
                float v = acc[mi][ni][r];
                f16 hi = (f16)v;
                Th[idx] = hi;
                Tl[idx] = (f16)(v - (float)hi);
            }
}

// ---------------------------------------------------------------------------
// K_yT: YT16[b][d][m] = Y16[b][m][d]   (grid (32,8,16), 64x64 tiles)
// ---------------------------------------------------------------------------
__global__ __launch_bounds__(256) void k_ytrans(const f16* __restrict__ Y16,
                                                f16* __restrict__ YT) {
    __shared__ __align__(16) f16 S[64][72];
    const int b = blockIdx.x, m0 = blockIdx.y * 64, d0 = blockIdx.z * 64;
    const int t = threadIdx.x;
    {
        int row = t >> 2, cg = (t & 3) * 16;
        const f16* src = Y16 + (size_t)(b * LK + m0 + row) * DIM + d0 + cg;
        *(uint4*)&S[row][cg] = *(const uint4*)src;
        *(uint4*)&S[row][cg + 8] = *(const uint4*)(src + 8);
    }
    __syncthreads();
    int dd = t >> 2, ms = (t & 3) * 16;
    union { f16 h[16]; uint4 u[2]; } o;
#pragma unroll
    for (int j = 0; j < 16; ++j) o.h[j] = S[ms + j][dd];
    f16* dst = YT + (size_t)(b * DIM + d0 + dd) * LK + m0 + ms;
    *(uint4*)dst = o.u[0];
    *(uint4*)(dst + 8) = o.u[1];
}

// ---------------------------------------------------------------------------
// K3: per (b, 64 q-rows): s = (Th+Tl) . Y16^T + z, softmax over 512 keys,
// write unnormalized P fp16 + row sums. grid (32,8), 512 thr (8 waves).
// Each wave owns 64 key-columns. glds staging, BK=32.
// LDS: Th 4KB | Tl 4KB | Y 32KB (contiguous for glds flat mapping).
// ---------------------------------------------------------------------------
__global__ __launch_bounds__(512) void k_attn(const f16* __restrict__ Th,
                                              const f16* __restrict__ Tl,
                                              const f16* __restrict__ Y16,
                                              const float* __restrict__ Z,
                                              f16* __restrict__ P,
                                              float* __restrict__ Lsum) {
    __shared__ __align__(16) f16 sS[20480];  // 40960 B
    __shared__ float redmax[64][8];
    __shared__ float redsum[64][8];
    const int b = blockIdx.x;
    const int l0 = blockIdx.y * 64;
    const int t = threadIdx.x;
    const int lane = t & 63, w = t >> 6;
    const int ln15 = lane & 15, q = lane >> 4;
    floatx4 acc[4][4] = {};  // [row-frag][col-frag within wave's 64 cols]

    for (int e0 = 0; e0 < DIM; e0 += 32) {
        __syncthreads();
#pragma unroll
        for (int is = 0; is < 5; ++is) {
            int ff = is * 8192 + t * 16;
            const f16* g;
            if (ff < 4096) {
                g = Th + (size_t)(b * LQ + l0 + (ff >> 6)) * DIM + e0 + ((ff & 63) >> 1);
            } else if (ff < 8192) {
                int f2 = ff - 4096;
                g = Tl + (size_t)(b * LQ + l0 + (f2 >> 6)) * DIM + e0 + ((f2 & 63) >> 1);
            } else {
                int f2 = ff - 8192;
                g = Y16 + (size_t)(b * LK + (f2 >> 6)) * DIM + e0 + ((f2 & 63) >> 1);
            }
            glds16(g, (char*)sS + ff);
        }
        __syncthreads();
        f16x8 th[4], tl[4];
#pragma unroll
        for (int mi = 0; mi < 4; ++mi) {
            th[mi] = *(const f16x8*)&sS[(mi * 16 + ln15) * 32 + q * 8];
            tl[mi] = *(const f16x8*)&sS[2048 + (mi * 16 + ln15) * 32 + q * 8];
        }
#pragma unroll
        for (int ni = 0; ni < 4; ++ni) {
            f16x8 y = *(const f16x8*)&sS[4096 + (w * 64 + ni * 16 + ln15) * 32 + q * 8];
#pragma unroll
            for (int mi = 0; mi < 4; ++mi) {
                acc[mi][ni] = MFMA16(th[mi], y, acc[mi][ni]);
                acc[mi][ni] = MFMA16(tl[mi], y, acc[mi][ni]);
            }
        }
    }

    // ---- softmax over 512 cols (8 waves x 64 cols) ----
    float zv[4];
#pragma unroll
    for (int ni = 0; ni < 4; ++ni) zv[ni] = Z[b * LK + w * 64 + ni * 16 + ln15];

    float rmx[4][4];
#pragma unroll
    for (int mi = 0; mi < 4; ++mi)
#pragma unroll
        for (int r = 0; r < 4; ++r) {
            float m = -3.0e38f;
#pragma unroll
            for (int ni = 0; ni < 4; ++ni) m = fmaxf(m, acc[mi][ni][r] + zv[ni]);
#pragma unroll
            for (int off = 1; off < 16; off <<= 1) m = fmaxf(m, __shfl_xor(m, off, 64));
            rmx[mi][r] = m;
        }
    if (ln15 == 0) {
#pragma unroll
        for (int mi = 0; mi < 4; ++mi)
#pragma unroll
            for (int r = 0; r < 4; ++r) redmax[mi * 16 + q * 4 + r][w] = rmx[mi][r];
    }
    __syncthreads();
#pragma unroll
    for (int mi = 0; mi < 4; ++mi)
#pragma unroll
        for (int r = 0; r < 4; ++r) {
            int row = mi * 16 + q * 4 + r;
            float m = redmax[row][0];
#pragma unroll
            for (int j = 1; j < 8; ++j) m = fmaxf(m, redmax[row][j]);
            rmx[mi][r] = m;
        }
    float rsm[4][4] = {};
#pragma unroll
    for (int mi = 0; mi < 4; ++mi)
#pragma unroll
        for (int ni = 0; ni < 4; ++ni)
#pragma unroll
            for (int r = 0; r < 4; ++r) {
                float e = __expf(acc[mi][ni][r] + zv[ni] - rmx[mi][r]);
                acc[mi][ni][r] = e;
                rsm[mi][r] += e;
            }
#pragma unroll
    for (int mi = 0; mi < 4; ++mi)
#pragma unroll
        for (int r = 0; r < 4; ++r) {
            float s = rsm[mi][r];
#pragma unroll
            for (int off = 1; off < 16; off <<= 1) s += __shfl_xor(s, off, 64);
            rsm[mi][r] = s;
        }
    if (ln15 == 0) {
#pragma unroll
        for (int mi = 0; mi < 4; ++mi)
#pragma unroll
            for (int r = 0; r < 4; ++r) redsum[mi * 16 + q * 4 + r][w] = rsm[mi][r];
    }
    __syncthreads();
    if (w == 0 && ln15 == 0) {
#pragma unroll
        for (int mi = 0; mi < 4; ++mi)
#pragma unroll
            for (int r = 0; r < 4; ++r) {
                int row = mi * 16 + q * 4 + r;
                float s = 0.f;
#pragma unroll
                for (int j = 0; j < 8; ++j) s += redsum[row][j];
                Lsum[b * LQ + l0 + row] = s;
            }
    }
#pragma unroll
    for (int mi = 0; mi < 4; ++mi)
#pragma unroll
        for (int ni = 0; ni < 4; ++ni)
#pragma unroll
            for (int r = 0; r < 4; ++r) {
                int row = l0 + mi * 16 + q * 4 + r;
                int col = w * 64 + ni * 16 + ln15;
                P[(size_t)(b * LQ + row) * LK + col] = (f16)acc[mi][ni][r];
            }
}

// ---------------------------------------------------------------------------
// K4: O = (P @ y) / Lsum  via YT16. grid (32,4,8), 128x128 tile, BK=32, glds.
// ---------------------------------------------------------------------------
__global__ __launch_bounds__(256) void k_pv(const f16* __restrict__ P,
                                            const f16* __restrict__ YT,
                                            const float* __restrict__ Lsum,
                                            float* __restrict__ O) {
    __shared__ __align__(16) f16 sA[128 * 32];
    __shared__ __align__(16) f16 sB[128 * 32];
    const int t = threadIdx.x;
    const int lane = t & 63, wid = t >> 6;
    const int ln15 = lane & 15, q = lane >> 4;
    const int wr = (wid >> 1) * 64, wc = (wid & 1) * 64;
    const int b = blockIdx.x, m0 = blockIdx.y * 128, n0 = blockIdx.z * 128;
    floatx4 acc[4][4] = {};
    for (int k0 = 0; k0 < LK; k0 += 32) {
        __syncthreads();
#pragma unroll
        for (int is = 0; is < 2; ++is) {
            int ff = is * 4096 + t * 16;
            int row = ff >> 6, col = (ff & 63) >> 1;
            glds16(P + (size_t)(b * LQ + m0 + row) * LK + k0 + col, (char*)sA + ff);
            glds16(YT + (size_t)(b * DIM + n0 + row) * LK + k0 + col, (char*)sB + ff);
        }
        __syncthreads();
        f16x8 a[4];
#pragma unroll
        for (int mi = 0; mi < 4; ++mi)
            a[mi] = *(const f16x8*)&sA[(wr + mi * 16 + ln15) * 32 + q * 8];
#pragma unroll
        for (int ni = 0; ni < 4; ++ni) {
            f16x8 bv = *(const f16x8*)&sB[(wc + ni * 16 + ln15) * 32 + q * 8];
#pragma unroll
            for (int mi = 0; mi < 4; ++mi) acc[mi][ni] = MFMA16(a[mi], bv, acc[mi][ni]);
        }
    }
    float invl[4][4];
#pragma unroll
    for (int mi = 0; mi < 4; ++mi)
#pragma unroll
        for (int r = 0; r < 4; ++r)
            invl[mi][r] = 1.0f / Lsum[b * LQ + m0 + wr + mi * 16 + q * 4 + r];
#pragma unroll
    for (int mi = 0; mi < 4; ++mi)
#pragma unroll
        for (int ni = 0; ni < 4; ++ni)
#pragma unroll
            for (int r = 0; r < 4; ++r)
                O[(size_t)(b * LQ + m0 + wr + mi * 16 + q * 4 + r) * DIM +
                  n0 + wc + ni * 16 + ln15] = acc[mi][ni][r] * invl[mi][r];
}

// ---------------------------------------------------------------------------
// Workspace layout (bytes), total ~88.3 MiB:
//   A:  0         X16 fp16 [16384][1024] (33,554,432); after k_tgemm reused
//                 for YT16 fp16 [32][1024][512]
//   B:  33554432  Y16 fp16 [32][512][1024] (33,554,432)
//   P:  67108864  P fp16 [32][512][512]    (16,777,216)
//   Gh: 83886080  (2,097,152)   Gl: 85983232 (2,097,152)
//   c:  88080384  (4096)  z: 88084480 (65536)  L: 88150016 (65536)
//   partial: 88215552 (65536)
// d_out doubles as Th|Tl fp16 scratch (33.5MB+33.5MB) between k_tgemm and
// k_attn; k_pv overwrites it with the final fp32 result.
// ---------------------------------------------------------------------------
extern "C" void kernel_launch(void* const* d_in, const int* in_sizes, int n_in,
                              void* d_out, int out_size, void* d_ws, size_t ws_size,
                              hipStream_t stream) {
    const float* ix = (const float*)d_in[0];
    const float* io = (const float*)d_in[1];
    const float* W = (const float*)d_in[2];
    const float* bb = (const float*)d_in[3];
    float* out = (float*)d_out;
    char* ws = (char*)d_ws;

    f16* X16 = (f16*)(ws);
    f16* YT16 = (f16*)(ws);  // same region, used after k_tgemm
    f16* Y16 = (f16*)(ws + 33554432);
    f16* P = (f16*)(ws + 67108864);
    f16* Gh = (f16*)(ws + 83886080);
    f16* Gl = (f16*)(ws + 85983232);
    float* c = (float*)(ws + 88080384);
    float* z = (float*)(ws + 88084480);
    float* L = (float*)(ws + 88150016);
    float* partial = (float*)(ws + 88215552);

    f16* Th = (f16*)d_out;
    f16* Tl = Th + (size_t)16384 * 1024;

    k_cvec1<<<dim3(16, 16), dim3(256), 0, stream>>>(W, bb, partial);
    k_cvec2<<<dim3(4), dim3(256), 0, stream>>>(partial, c);
    k_gram<<<dim3(16, 16), dim3(256), 0, stream>>>(W, Gh, Gl);
    k_prep_y<<<dim3(4096), dim3(256), 0, stream>>>(io, c, Y16, z);
    k_xsplit<<<dim3(8192), dim3(256), 0, stream>>>(ix, X16);
    k_tgemm<<<dim3(128, 8), dim3(256), 0, stream>>>(X16, Gh, Gl, Th, Tl);
    k_ytrans<<<dim3(32, 8, 16), dim3(256), 0, stream>>>(Y16, YT16);
    k_attn<<<dim3(32, 8), dim3(512), 0, stream>>>(Th, Tl, Y16, z, P, L);
    k_pv<<<dim3(32, 4, 8), dim3(256), 0, stream>>>(P, YT16, L, out);
}

// Round 4
// 342.158 us; speedup vs baseline: 1.6906x; 1.1757x over previous
//
#include <hip/hip_runtime.h>

typedef _Float16 f16;
typedef __attribute__((ext_vector_type(8))) _Float16 f16x8;
typedef __attribute__((ext_vector_type(4))) _Float16 f16x4;
typedef __attribute__((ext_vector_type(4))) float floatx4;

#define MFMA16(a, b, c) __builtin_amdgcn_mfma_f32_16x16x32_f16(a, b, c, 0, 0, 0)

#define BATCH 32
#define LQ 512
#define LK 512
#define DIM 1024

// async global->LDS, 16B per lane. LDS dest must be base + lane*16 within wave.
__device__ __forceinline__ void glds16(const void* g, void* l) {
    __builtin_amdgcn_global_load_lds(
        (const __attribute__((address_space(1))) unsigned int*)g,
        (__attribute__((address_space(3))) unsigned int*)l, 16, 0, 0);
}

// ---------------------------------------------------------------------------
// K0a stage 1: partial[ec][d] = sum_{e in 64-chunk ec} W[e][d]*bias[e]
// ---------------------------------------------------------------------------
__global__ __launch_bounds__(256) void k_cvec1(const float* __restrict__ W,
                                               const float* __restrict__ bias,
                                               float* __restrict__ partial) {
    __shared__ float red[256];
    int t = threadIdx.x;
    int dd = t & 63, eg = t >> 6;
    int d = blockIdx.x * 64 + dd;
    int e0 = blockIdx.y * 64 + eg * 16;
    float s = 0.f;
#pragma unroll
    for (int i = 0; i < 16; ++i)
        s += W[(size_t)(e0 + i) * DIM + d] * bias[e0 + i];
    red[t] = s;
    __syncthreads();
    if (eg == 0)
        partial[blockIdx.y * DIM + d] =
            red[dd] + red[64 + dd] + red[128 + dd] + red[192 + dd];
}

// K0a stage 2: c[d] = sum_ec partial[ec][d]
__global__ __launch_bounds__(256) void k_cvec2(const float* __restrict__ partial,
                                               float* __restrict__ c) {
    int d = blockIdx.x * 256 + threadIdx.x;
    float s = 0.f;
#pragma unroll
    for (int j = 0; j < 16; ++j) s += partial[j * DIM + d];
    c[d] = s;
}

// ---------------------------------------------------------------------------
// K0b: Y16 = fp16(Y) and z[row] = c . Y[row]   (grid 4096 x 256)
// ---------------------------------------------------------------------------
__global__ __launch_bounds__(256) void k_prep_y(const float* __restrict__ Y,
                                                const float* __restrict__ c,
                                                f16* __restrict__ Y16,
                                                float* __restrict__ z) {
    int wid = threadIdx.x >> 6, lane = threadIdx.x & 63;
    int row = blockIdx.x * 4 + wid;
    const float* yr = Y + (size_t)row * DIM;
    f16* orow = Y16 + (size_t)row * DIM;
    float s = 0.f;
#pragma unroll
    for (int k = 0; k < 4; ++k) {
        int d = k * 256 + lane * 4;
        floatx4 v = *(const floatx4*)(yr + d);
        floatx4 cv = *(const floatx4*)(c + d);
        s += v[0] * cv[0] + v[1] * cv[1] + v[2] * cv[2] + v[3] * cv[3];
        f16x4 o;
        o[0] = (f16)v[0]; o[1] = (f16)v[1]; o[2] = (f16)v[2]; o[3] = (f16)v[3];
        *(f16x4*)(orow + d) = o;
    }
#pragma unroll
    for (int off = 32; off; off >>= 1) s += __shfl_down(s, off, 64);
    if (lane == 0) z[row] = s;
}

// ---------------------------------------------------------------------------
// K0c: X16 = fp16(X)
// ---------------------------------------------------------------------------
__global__ __launch_bounds__(256) void k_xsplit(const float* __restrict__ X,
                                                f16* __restrict__ X16) {
    size_t i = ((size_t)blockIdx.x * 256 + threadIdx.x) * 8;
    floatx4 a = *(const floatx4*)(X + i);
    floatx4 b = *(const floatx4*)(X + i + 4);
    f16x8 o;
    o[0] = (f16)a[0]; o[1] = (f16)a[1]; o[2] = (f16)a[2]; o[3] = (f16)a[3];
    o[4] = (f16)b[0]; o[5] = (f16)b[1]; o[6] = (f16)b[2]; o[7] = (f16)b[3];
    *(f16x8*)(X16 + i) = o;
}

// ---------------------------------------------------------------------------
// K1: Gh = fp16(W^T W), single fp16 pass. grid (16,16), 64x64 tile.
// Precision: 1-pass adds only ~2e-3 score sigma (vs 0.108 budget).
// ---------------------------------------------------------------------------
__global__ __launch_bounds__(256) void k_gram(const float* __restrict__ W,
                                              f16* __restrict__ Gh) {
    __shared__ __align__(16) f16 As[64][40];  // [i][e], pad->2-way max (free)
    __shared__ __align__(16) f16 Bs[64][40];
    int t = threadIdx.x;
    int lane = t & 63, wid = t >> 6;
    int ln15 = lane & 15, q = lane >> 4;
    int wr = (wid >> 1) * 32, wc = (wid & 1) * 32;
    int i0 = blockIdx.x * 64, j0 = blockIdx.y * 64;
    floatx4 acc[2][2] = {};
    for (int e0 = 0; e0 < DIM; e0 += 32) {
        __syncthreads();
        {
            int ee = t >> 3;
            int c8 = (t & 7) * 8;
            const float* src = W + (size_t)(e0 + ee) * DIM;
#pragma unroll
            for (int h = 0; h < 2; ++h) {
                floatx4 v = *(const floatx4*)(src + i0 + c8 + h * 4);
#pragma unroll
                for (int j = 0; j < 4; ++j) As[c8 + h * 4 + j][ee] = (f16)v[j];
                floatx4 u = *(const floatx4*)(src + j0 + c8 + h * 4);
#pragma unroll
                for (int j = 0; j < 4; ++j) Bs[c8 + h * 4 + j][ee] = (f16)u[j];
            }
        }
        __syncthreads();
        f16x8 a[2], b[2];
#pragma unroll
        for (int mi = 0; mi < 2; ++mi)
            a[mi] = *(const f16x8*)&As[wr + mi * 16 + ln15][q * 8];
#pragma unroll
        for (int ni = 0; ni < 2; ++ni)
            b[ni] = *(const f16x8*)&Bs[wc + ni * 16 + ln15][q * 8];
#pragma unroll
        for (int mi = 0; mi < 2; ++mi)
#pragma unroll
            for (int ni = 0; ni < 2; ++ni)
                acc[mi][ni] = MFMA16(a[mi], b[ni], acc[mi][ni]);
    }
#pragma unroll
    for (int mi = 0; mi < 2; ++mi)
#pragma unroll
        for (int ni = 0; ni < 2; ++ni)
#pragma unroll
            for (int r = 0; r < 4; ++r) {
                int i = i0 + wr + mi * 16 + q * 4 + r;
                int j = j0 + wc + ni * 16 + ln15;
                Gh[(size_t)i * DIM + j] = (f16)acc[mi][ni][r];
            }
}

// ---------------------------------------------------------------------------
// K2: Th = fp16(X16 @ Gh), single pass. M=16384, N=K=1024.
// 128x128 tile, BK=32, glds staging. -> d_out scratch.
// ---------------------------------------------------------------------------
__global__ __launch_bounds__(256) void k_tgemm(const f16* __restrict__ X16,
                                               const f16* __restrict__ Gh,
                                               f16* __restrict__ Th) {
    __shared__ __align__(16) f16 sA[128 * 32];
    __shared__ __align__(16) f16 sB[128 * 32];
    const int t = threadIdx.x;
    const int lane = t & 63, wid = t >> 6;
    const int ln15 = lane & 15, q = lane >> 4;
    const int wr = (wid >> 1) * 64, wc = (wid & 1) * 64;
    const int m0 = blockIdx.x * 128, n0 = blockIdx.y * 128;
    floatx4 acc[4][4] = {};
    for (int e0 = 0; e0 < DIM; e0 += 32) {
        __syncthreads();
#pragma unroll
        for (int is = 0; is < 2; ++is) {
            int ff = is * 4096 + t * 16;            // byte offset in 8KB tile
            int row = ff >> 6, col = (ff & 63) >> 1;
            glds16(X16 + (size_t)(m0 + row) * DIM + e0 + col, (char*)sA + ff);
            glds16(Gh + (size_t)(n0 + row) * DIM + e0 + col, (char*)sB + ff);
        }
        __syncthreads();
        f16x8 a[4];
#pragma unroll
        for (int mi = 0; mi < 4; ++mi)
            a[mi] = *(const f16x8*)&sA[(wr + mi * 16 + ln15) * 32 + q * 8];
#pragma unroll
        for (int ni = 0; ni < 4; ++ni) {
            f16x8 bv = *(const f16x8*)&sB[(wc + ni * 16 + ln15) * 32 + q * 8];
#pragma unroll
            for (int mi = 0; mi < 4; ++mi)
                acc[mi][ni] = MFMA16(a[mi], bv, acc[mi][ni]);
        }
    }
#pragma unroll
    for (int mi = 0; mi < 4; ++mi)
#pragma unroll
        for (int ni = 0; ni < 4; ++ni)
#pragma unroll
            for (int r = 0; r < 4; ++r)
                Th[(size_t)(m0 + wr + mi * 16 + q * 4 + r) * DIM +
                   n0 + wc + ni * 16 + ln15] = (f16)acc[mi][ni][r];
}

// ---------------------------------------------------------------------------
// K_yT: YT16[b][d][m] = Y16[b][m][d]   (grid (32,8,16), 64x64 tiles)
// ---------------------------------------------------------------------------
__global__ __launch_bounds__(256) void k_ytrans(const f16* __restrict__ Y16,
                                                f16* __restrict__ YT) {
    __shared__ __align__(16) f16 S[64][72];
    const int b = blockIdx.x, m0 = blockIdx.y * 64, d0 = blockIdx.z * 64;
    const int t = threadIdx.x;
    {
        int row = t >> 2, cg = (t & 3) * 16;
        const f16* src = Y16 + (size_t)(b * LK + m0 + row) * DIM + d0 + cg;
        *(uint4*)&S[row][cg] = *(const uint4*)src;
        *(uint4*)&S[row][cg + 8] = *(const uint4*)(src + 8);
    }
    __syncthreads();
    int dd = t >> 2, ms = (t & 3) * 16;
    union { f16 h[16]; uint4 u[2]; } o;
#pragma unroll
    for (int j = 0; j < 16; ++j) o.h[j] = S[ms + j][dd];
    f16* dst = YT + (size_t)(b * DIM + d0 + dd) * LK + m0 + ms;
    *(uint4*)dst = o.u[0];
    *(uint4*)(dst + 8) = o.u[1];
}

// ---------------------------------------------------------------------------
// K3: per (b, 64 q-rows): s = Th . Y16^T + z, softmax over 512 keys,
// write unnormalized P fp16 + row sums. grid (32,8), 512 thr (8 waves).
// LDS: Th 4KB | Y 32KB contiguous (glds flat mapping), BK=32.
// ---------------------------------------------------------------------------
__global__ __launch_bounds__(512) void k_attn(const f16* __restrict__ Th,
                                              const f16* __restrict__ Y16,
                                              const float* __restrict__ Z,
                                              f16* __restrict__ P,
                                              float* __restrict__ Lsum) {
    __shared__ __align__(16) f16 sS[18432];  // 36864 B
    __shared__ float redmax[64][8];
    __shared__ float redsum[64][8];
    const int b = blockIdx.x;
    const int l0 = blockIdx.y * 64;
    const int t = threadIdx.x;
    const int lane = t & 63, w = t >> 6;
    const int ln15 = lane & 15, q = lane >> 4;
    floatx4 acc[4][4] = {};

    for (int e0 = 0; e0 < DIM; e0 += 32) {
        __syncthreads();
#pragma unroll
        for (int is = 0; is < 5; ++is) {
            int ff = is * 8192 + t * 16;
            if (ff < 36864) {  // wave-uniform: last chunk only waves 0-3
                const f16* g;
                if (ff < 4096) {
                    g = Th + (size_t)(b * LQ + l0 + (ff >> 6)) * DIM + e0 + ((ff & 63) >> 1);
                } else {
                    int f2 = ff - 4096;
                    g = Y16 + (size_t)(b * LK + (f2 >> 6)) * DIM + e0 + ((f2 & 63) >> 1);
                }
                glds16(g, (char*)sS + ff);
            }
        }
        __syncthreads();
        f16x8 th[4];
#pragma unroll
        for (int mi = 0; mi < 4; ++mi)
            th[mi] = *(const f16x8*)&sS[(mi * 16 + ln15) * 32 + q * 8];
#pragma unroll
        for (int ni = 0; ni < 4; ++ni) {
            f16x8 y = *(const f16x8*)&sS[2048 + (w * 64 + ni * 16 + ln15) * 32 + q * 8];
#pragma unroll
            for (int mi = 0; mi < 4; ++mi)
                acc[mi][ni] = MFMA16(th[mi], y, acc[mi][ni]);
        }
    }

    // ---- softmax over 512 cols (8 waves x 64 cols) ----
    float zv[4];
#pragma unroll
    for (int ni = 0; ni < 4; ++ni) zv[ni] = Z[b * LK + w * 64 + ni * 16 + ln15];

    float rmx[4][4];
#pragma unroll
    for (int mi = 0; mi < 4; ++mi)
#pragma unroll
        for (int r = 0; r < 4; ++r) {
            float m = -3.0e38f;
#pragma unroll
            for (int ni = 0; ni < 4; ++ni) m = fmaxf(m, acc[mi][ni][r] + zv[ni]);
#pragma unroll
            for (int off = 1; off < 16; off <<= 1) m = fmaxf(m, __shfl_xor(m, off, 64));
            rmx[mi][r] = m;
        }
    if (ln15 == 0) {
#pragma unroll
        for (int mi = 0; mi < 4; ++mi)
#pragma unroll
            for (int r = 0; r < 4; ++r) redmax[mi * 16 + q * 4 + r][w] = rmx[mi][r];
    }
    __syncthreads();
#pragma unroll
    for (int mi = 0; mi < 4; ++mi)
#pragma unroll
        for (int r = 0; r < 4; ++r) {
            int row = mi * 16 + q * 4 + r;
            float m = redmax[row][0];
#pragma unroll
            for (int j = 1; j < 8; ++j) m = fmaxf(m, redmax[row][j]);
            rmx[mi][r] = m;
        }
    float rsm[4][4] = {};
#pragma unroll
    for (int mi = 0; mi < 4; ++mi)
#pragma unroll
        for (int ni = 0; ni < 4; ++ni)
#pragma unroll
            for (int r = 0; r < 4; ++r) {
                float e = __expf(acc[mi][ni][r] + zv[ni] - rmx[mi][r]);
                acc[mi][ni][r] = e;
                rsm[mi][r] += e;
            }
#pragma unroll
    for (int mi = 0; mi < 4; ++mi)
#pragma unroll
        for (int r = 0; r < 4; ++r) {
            float s = rsm[mi][r];
#pragma unroll
            for (int off = 1; off < 16; off <<= 1) s += __shfl_xor(s, off, 64);
            rsm[mi][r] = s;
        }
    if (ln15 == 0) {
#pragma unroll
        for (int mi = 0; mi < 4; ++mi)
#pragma unroll
            for (int r = 0; r < 4; ++r) redsum[mi * 16 + q * 4 + r][w] = rsm[mi][r];
    }
    __syncthreads();
    if (w == 0 && ln15 == 0) {
#pragma unroll
        for (int mi = 0; mi < 4; ++mi)
#pragma unroll
            for (int r = 0; r < 4; ++r) {
                int row = mi * 16 + q * 4 + r;
                float s = 0.f;
#pragma unroll
                for (int j = 0; j < 8; ++j) s += redsum[row][j];
                Lsum[b * LQ + l0 + row] = s;
            }
    }
#pragma unroll
    for (int mi = 0; mi < 4; ++mi)
#pragma unroll
        for (int ni = 0; ni < 4; ++ni)
#pragma unroll
            for (int r = 0; r < 4; ++r) {
                int row = l0 + mi * 16 + q * 4 + r;
                int col = w * 64 + ni * 16 + ln15;
                P[(size_t)(b * LQ + row) * LK + col] = (f16)acc[mi][ni][r];
            }
}

// ---------------------------------------------------------------------------
// K4: O = (P @ y) / Lsum  via YT16. grid (32,4,8), 128x128 tile, BK=32, glds.
// ---------------------------------------------------------------------------
__global__ __launch_bounds__(256) void k_pv(const f16* __restrict__ P,
                                            const f16* __restrict__ YT,
                                            const float* __restrict__ Lsum,
                                            float* __restrict__ O) {
    __shared__ __align__(16) f16 sA[128 * 32];
    __shared__ __align__(16) f16 sB[128 * 32];
    const int t = threadIdx.x;
    const int lane = t & 63, wid = t >> 6;
    const int ln15 = lane & 15, q = lane >> 4;
    const int wr = (wid >> 1) * 64, wc = (wid & 1) * 64;
    const int b = blockIdx.x, m0 = blockIdx.y * 128, n0 = blockIdx.z * 128;
    floatx4 acc[4][4] = {};
    for (int k0 = 0; k0 < LK; k0 += 32) {
        __syncthreads();
#pragma unroll
        for (int is = 0; is < 2; ++is) {
            int ff = is * 4096 + t * 16;
            int row = ff >> 6, col = (ff & 63) >> 1;
            glds16(P + (size_t)(b * LQ + m0 + row) * LK + k0 + col, (char*)sA + ff);
            glds16(YT + (size_t)(b * DIM + n0 + row) * LK + k0 + col, (char*)sB + ff);
        }
        __syncthreads();
        f16x8 a[4];
#pragma unroll
        for (int mi = 0; mi < 4; ++mi)
            a[mi] = *(const f16x8*)&sA[(wr + mi * 16 + ln15) * 32 + q * 8];
#pragma unroll
        for (int ni = 0; ni < 4; ++ni) {
            f16x8 bv = *(const f16x8*)&sB[(wc + ni * 16 + ln15) * 32 + q * 8];
#pragma unroll
            for (int mi = 0; mi < 4; ++mi) acc[mi][ni] = MFMA16(a[mi], bv, acc[mi][ni]);
        }
    }
    float invl[4][4];
#pragma unroll
    for (int mi = 0; mi < 4; ++mi)
#pragma unroll
        for (int r = 0; r < 4; ++r)
            invl[mi][r] = 1.0f / Lsum[b * LQ + m0 + wr + mi * 16 + q * 4 + r];
#pragma unroll
    for (int mi = 0; mi < 4; ++mi)
#pragma unroll
        for (int ni = 0; ni < 4; ++ni)
#pragma unroll
            for (int r = 0; r < 4; ++r)
                O[(size_t)(b * LQ + m0 + wr + mi * 16 + q * 4 + r) * DIM +
                  n0 + wc + ni * 16 + ln15] = acc[mi][ni][r] * invl[mi][r];
}

// ---------------------------------------------------------------------------
// Workspace layout (bytes), total ~86 MiB:
//   A:  0         X16 fp16 [16384][1024] (33,554,432); reused as YT16 after tgemm
//   B:  33554432  Y16 fp16 [32][512][1024] (33,554,432)
//   P:  67108864  P fp16 [32][512][512]    (16,777,216)
//   Gh: 83886080  (2,097,152)
//   c:  85983232 (4096)  z: 85987328 (65536)  L: 86052864 (65536)
//   partial: 86118400 (65536)
// d_out doubles as Th fp16 scratch (32 MB) between k_tgemm and k_attn;
// k_pv overwrites it with the final fp32 result.
// ---------------------------------------------------------------------------
extern "C" void kernel_launch(void* const* d_in, const int* in_sizes, int n_in,
                              void* d_out, int out_size, void* d_ws, size_t ws_size,
                              hipStream_t stream) {
    const float* ix = (const float*)d_in[0];
    const float* io = (const float*)d_in[1];
    const float* W = (const float*)d_in[2];
    const float* bb = (const float*)d_in[3];
    float* out = (float*)d_out;
    char* ws = (char*)d_ws;

    f16* X16 = (f16*)(ws);
    f16* YT16 = (f16*)(ws);  // same region, used after k_tgemm
    f16* Y16 = (f16*)(ws + 33554432);
    f16* P = (f16*)(ws + 67108864);
    f16* Gh = (f16*)(ws + 83886080);
    float* c = (float*)(ws + 85983232);
    float* z = (float*)(ws + 85987328);
    float* L = (float*)(ws + 86052864);
    float* partial = (float*)(ws + 86118400);

    f16* Th = (f16*)d_out;

    k_cvec1<<<dim3(16, 16), dim3(256), 0, stream>>>(W, bb, partial);
    k_cvec2<<<dim3(4), dim3(256), 0, stream>>>(partial, c);
    k_gram<<<dim3(16, 16), dim3(256), 0, stream>>>(W, Gh);
    k_prep_y<<<dim3(4096), dim3(256), 0, stream>>>(io, c, Y16, z);
    k_xsplit<<<dim3(8192), dim3(256), 0, stream>>>(ix, X16);
    k_tgemm<<<dim3(128, 8), dim3(256), 0, stream>>>(X16, Gh, Th);
    k_ytrans<<<dim3(32, 8, 16), dim3(256), 0, stream>>>(Y16, YT16);
    k_attn<<<dim3(32, 8), dim3(512), 0, stream>>>(Th, Y16, z, P, L);
    k_pv<<<dim3(32, 4, 8), dim3(256), 0, stream>>>(P, YT16, L, out);
}